// Round 9
// baseline (738.476 us; speedup 1.0000x reference)
//
#include <hip/hip_runtime.h>

// GCN forward on MI355X (gfx950).
// R9: bucket-segmented SpMM with LDS f32 atomic accumulation (128-row
// buckets, acc[128][64] in LDS) — deletes the row-sort pass (k_bfinal/
// pairs/offs2) and replaces both gathers. GEMM1 and bscatter fused into
// one kernel (independent work, block-range split). 5 dispatches.

#define N_NODES 50000
#define N_EDGES 800000
#define IN_DIM  128
#define HID_DIM 64
#define OUT_DIM 64

#define RB   128                     // rows per bucket
#define NB   ((N_NODES + RB - 1) / RB)            // 391
#define EPB  4096                    // edges per bscatter block
#define NBLK_E ((N_EDGES + EPB - 1) / EPB)        // 196
#define BCAP 2560                    // padded bucket region; E=2046, sigma~45
#define GEMM1_GRID ((N_NODES + 31) / 32)          // 1563

typedef __attribute__((ext_vector_type(8))) short bf16x8;
typedef __attribute__((ext_vector_type(4))) float f32x4;

__device__ inline unsigned short f2bf(float x) {   // RNE fp32 -> bf16
    unsigned u = __float_as_uint(x);
    return (unsigned short)((u + 0x7FFFu + ((u >> 16) & 1u)) >> 16);
}
__device__ inline float bf2f(unsigned v) {
    return __uint_as_float(v << 16);
}

// ---------------- prep: weight transpose+bf16 convert, bcur zero ------
// grid = 49: blocks 0-31 -> Wt1, 32-47 -> Wt2, 48 -> zero bcur.
__global__ __launch_bounds__(256) void k_prep(
    const float* __restrict__ W1, unsigned short* __restrict__ Wt1,
    const float* __restrict__ W2, unsigned short* __restrict__ Wt2,
    int* __restrict__ bcur)
{
    int b = blockIdx.x, t = threadIdx.x;
    if (b < 32) {                       // IN_DIM*HID_DIM = 8192 = 32*256
        int e = b * 256 + t;
        int c = e / IN_DIM, k = e % IN_DIM;
        Wt1[c * IN_DIM + k] = f2bf(W1[k * HID_DIM + c]);
    } else if (b < 48) {                // HID_DIM*OUT_DIM = 4096 = 16*256
        int e2 = (b - 32) * 256 + t;
        int c = e2 / HID_DIM, k = e2 % HID_DIM;
        Wt2[c * HID_DIM + k] = f2bf(W2[k * OUT_DIM + c]);
    } else {
        for (int i = t; i < NB; i += 256) bcur[i] = 0;
    }
}

// ---------------- MFMA GEMM body (shared by mega1 and gemm2) ----------
// 32 rows/block, 4 waves. Both LDS tiles XOR-swizzled (byte ^= (row&7)<<4).
template <int K, bool IN_BF16>
__device__ __forceinline__ void gemm_body(
    unsigned short* __restrict__ Al, unsigned short* __restrict__ Bl,
    const void* __restrict__ Xv, const unsigned short* __restrict__ Wt,
    unsigned short* __restrict__ out, int bid, int t)
{
    int m0 = bid * 32;
    #pragma unroll
    for (int i = 0; i < K / 32; ++i) {
        int u4 = i * 256 + t;                 // uint4 index
        int col = (u4 * 8) / K, k = (u4 * 8) % K;
        uint4 w = ((const uint4*)Wt)[u4];
        int byte = (col * K + k) * 2;
        byte ^= ((col & 7) << 4);
        *(uint4*)((char*)Bl + byte) = w;
    }
    if (IN_BF16) {
        const unsigned short* X = (const unsigned short*)Xv;
        int row = t / (K / 8), k = (t % (K / 8)) * 8;
        int grow = m0 + row;
        uint4 v = make_uint4(0, 0, 0, 0);
        if (grow < N_NODES)
            v = *(const uint4*)(X + (size_t)grow * K + k);
        int byte = (row * K + k) * 2;
        byte ^= ((row & 7) << 4);
        *(uint4*)((char*)Al + byte) = v;
    } else {
        const float* X = (const float*)Xv;
        #pragma unroll
        for (int i = 0; i < K / 64; ++i) {
            int f8 = i * 256 + t;             // 8-float group
            int row = (f8 * 8) / K, k = (f8 * 8) % K;
            int grow = m0 + row;
            float4 xa = make_float4(0.f, 0.f, 0.f, 0.f), xb = xa;
            if (grow < N_NODES) {
                const float4* src = (const float4*)(X + (size_t)grow * K + k);
                xa = src[0];
                xb = src[1];
            }
            uint4 v;
            v.x = (unsigned)f2bf(xa.x) | ((unsigned)f2bf(xa.y) << 16);
            v.y = (unsigned)f2bf(xa.z) | ((unsigned)f2bf(xa.w) << 16);
            v.z = (unsigned)f2bf(xb.x) | ((unsigned)f2bf(xb.y) << 16);
            v.w = (unsigned)f2bf(xb.z) | ((unsigned)f2bf(xb.w) << 16);
            int byte = (row * K + k) * 2;
            byte ^= ((row & 7) << 4);
            *(uint4*)((char*)Al + byte) = v;
        }
    }
    __syncthreads();

    int w = t >> 6, l = t & 63;
    int lr0 = (w & 1) * 16;
    int c0  = (w >> 1) * 32;
    int lrow = lr0 + (l & 15);
    int kb = (l >> 4) * 8;
    int col0 = c0 + (l & 15), col1 = col0 + 16;
    f32x4 acc0 = {0.f, 0.f, 0.f, 0.f}, acc1 = {0.f, 0.f, 0.f, 0.f};
    #pragma unroll
    for (int kc = 0; kc < K / 32; ++kc) {
        int ka = kc * 32 + kb;
        int ab = (lrow * K + ka) * 2;  ab ^= ((lrow & 7) << 4);
        int bb0 = (col0 * K + ka) * 2; bb0 ^= ((col0 & 7) << 4);
        int bb1 = (col1 * K + ka) * 2; bb1 ^= ((col1 & 7) << 4);
        bf16x8 a  = *(const bf16x8*)((const char*)Al + ab);
        bf16x8 b0 = *(const bf16x8*)((const char*)Bl + bb0);
        bf16x8 b1 = *(const bf16x8*)((const char*)Bl + bb1);
        acc0 = __builtin_amdgcn_mfma_f32_16x16x32_bf16(a, b0, acc0, 0, 0, 0);
        acc1 = __builtin_amdgcn_mfma_f32_16x16x32_bf16(a, b1, acc1, 0, 0, 0);
    }
    int grow0 = m0 + lr0 + (l >> 4) * 4;
    #pragma unroll
    for (int j = 0; j < 4; ++j) {
        int gr = grow0 + j;
        if (gr < N_NODES) {
            out[(size_t)gr * 64 + col0] = f2bf(acc0[j]);
            out[(size_t)gr * 64 + col1] = f2bf(acc1[j]);
        }
    }
}

// ---------------- mega1: GEMM1 (blocks < GEMM1_GRID) || bscatter ------
// Independent work overlapped in one dispatch via block-range split.
// Shared memory union: GEMM needs 24KB (Al 8K + Bl 16K); bscatter ~3.1KB.
__global__ __launch_bounds__(256) void k_mega1(
    const float* __restrict__ X, const unsigned short* __restrict__ Wt1,
    unsigned short* __restrict__ support,
    const int* __restrict__ erow, const int* __restrict__ ecol,
    const float* __restrict__ eval_, int* __restrict__ bcur,
    uint2* __restrict__ bucketed)
{
    __shared__ __align__(16) unsigned char smem[24576];
    int t = threadIdx.x;
    if (blockIdx.x < GEMM1_GRID) {
        gemm_body<IN_DIM, false>((unsigned short*)smem,
                                 (unsigned short*)(smem + 8192),
                                 X, Wt1, support, blockIdx.x, t);
        return;
    }
    // ---- bscatter: edges into padded bucket regions ----
    // word0 = col (16b) | rowlow (7b) << 16; word1 = val bits.
    int* lc    = (int*)smem;
    int* lbase = lc + NB;
    int blk = blockIdx.x - GEMM1_GRID;
    for (int i = t; i < NB; i += 256) lc[i] = 0;
    __syncthreads();
    int base = blk * EPB;
    int bkt[16], rnk[16];
    #pragma unroll 4
    for (int i = 0; i < 16; ++i) {
        int e = base + i * 256 + t;
        bkt[i] = -1;
        if (e < N_EDGES) {
            bkt[i] = erow[e] >> 7;
            rnk[i] = atomicAdd(&lc[bkt[i]], 1);
        }
    }
    __syncthreads();
    for (int i = t; i < NB; i += 256)
        lbase[i] = lc[i] ? atomicAdd(&bcur[i], lc[i]) : 0;
    __syncthreads();
    #pragma unroll 4
    for (int i = 0; i < 16; ++i) {
        int e = base + i * 256 + t;
        if (bkt[i] >= 0) {
            unsigned r = (unsigned)erow[e];
            unsigned w0 = (unsigned)ecol[e] | ((r & 127u) << 16);
            bucketed[(size_t)bkt[i] * BCAP + lbase[bkt[i]] + rnk[i]] =
                make_uint2(w0, __float_as_uint(eval_[e]));
        }
    }
}

// ---------------- GEMM2 standalone (K=64, bf16 in) --------------------
__global__ __launch_bounds__(256) void k_gemm2(
    const unsigned short* __restrict__ X, const unsigned short* __restrict__ Wt,
    unsigned short* __restrict__ out)
{
    __shared__ unsigned short Al[32 * HID_DIM];
    __shared__ unsigned short Bl[64 * HID_DIM];
    gemm_body<HID_DIM, true>(Al, Bl, X, Wt, out, blockIdx.x, threadIdx.x);
}

// ---------------- bucket-segmented SpMM ------------------------------
// One block per 128-row bucket; 16 waves stream the bucket's edges from
// `bucketed` (unsorted within bucket). Per edge: scalar pair load, 128B
// random dense read (L2-resident), ds_add_f32 into acc[rowlow][lane]
// (2 lanes/bank = conflict-free). Then bias/relu + contiguous writeout.
template <bool APPLY_RELU, bool OUT_BF16>
__global__ __launch_bounds__(1024) void k_spmm(
    const int* __restrict__ bcur, const uint2* __restrict__ bucketed,
    const unsigned short* __restrict__ dense, const float* __restrict__ bias,
    void* __restrict__ outp)
{
    __shared__ float acc[RB * 64];      // 32 KB
    int t = threadIdx.x, b = blockIdx.x;
    #pragma unroll
    for (int i = 0; i < (RB * 64) / 1024; ++i) acc[t + i * 1024] = 0.f;
    __syncthreads();
    int ne = bcur[b];
    int wv = __builtin_amdgcn_readfirstlane(t >> 6);
    int d = t & 63;
    const uint2* ep = bucketed + (size_t)b * BCAP;
    int chunk = (ne + 15) >> 4;
    int i0 = wv * chunk;
    int i1 = min(i0 + chunk, ne);
    int i = i0;
    for (; i + 4 <= i1; i += 4) {
        uint2 p0 = ep[i], p1 = ep[i + 1], p2 = ep[i + 2], p3 = ep[i + 3];
        float v0 = bf2f(dense[(size_t)(p0.x & 0xFFFFu) * 64u + d]);
        float v1 = bf2f(dense[(size_t)(p1.x & 0xFFFFu) * 64u + d]);
        float v2 = bf2f(dense[(size_t)(p2.x & 0xFFFFu) * 64u + d]);
        float v3 = bf2f(dense[(size_t)(p3.x & 0xFFFFu) * 64u + d]);
        atomicAdd(&acc[((p0.x >> 16) & 127u) * 64 + d], __uint_as_float(p0.y) * v0);
        atomicAdd(&acc[((p1.x >> 16) & 127u) * 64 + d], __uint_as_float(p1.y) * v1);
        atomicAdd(&acc[((p2.x >> 16) & 127u) * 64 + d], __uint_as_float(p2.y) * v2);
        atomicAdd(&acc[((p3.x >> 16) & 127u) * 64 + d], __uint_as_float(p3.y) * v3);
    }
    for (; i < i1; ++i) {
        uint2 p = ep[i];
        float v = bf2f(dense[(size_t)(p.x & 0xFFFFu) * 64u + d]);
        atomicAdd(&acc[((p.x >> 16) & 127u) * 64 + d], __uint_as_float(p.y) * v);
    }
    __syncthreads();
    #pragma unroll
    for (int it = 0; it < (RB * 64) / 1024; ++it) {
        int i2 = t + it * 1024;
        int gr = b * RB + (i2 >> 6);
        if (gr < N_NODES) {
            float v = acc[i2] + bias[i2 & 63];
            if (APPLY_RELU) v = fmaxf(v, 0.f);
            if (OUT_BF16)
                ((unsigned short*)outp)[(size_t)gr * 64 + (i2 & 63)] = f2bf(v);
            else
                ((float*)outp)[(size_t)gr * 64 + (i2 & 63)] = v;
        }
    }
}

extern "C" void kernel_launch(void* const* d_in, const int* in_sizes, int n_in,
                              void* d_out, int out_size, void* d_ws, size_t ws_size,
                              hipStream_t stream)
{
    const float* x     = (const float*)d_in[0];
    const int*   erow  = (const int*)d_in[1];
    const int*   ecol  = (const int*)d_in[2];
    const float* eval_ = (const float*)d_in[3];
    const float* W1    = (const float*)d_in[4];
    const float* b1    = (const float*)d_in[5];
    const float* W2    = (const float*)d_in[6];
    const float* b2    = (const float*)d_in[7];
    float* out = (float*)d_out;

    // ws (~21 MB): bucketed 391*2560*8 = 8.0MB | support bf16 6.4MB |
    // agg1 bf16 6.4MB | Wt1 16KB | Wt2 8KB | bcur 391 ints.
    // bucketed survives both spmm passes (no aliasing).
    uint2* bucketed = (uint2*)d_ws;
    unsigned short* support = (unsigned short*)(bucketed + (size_t)NB * BCAP);
    unsigned short* agg1 = support + (size_t)N_NODES * 64;
    unsigned short* Wt1 = agg1 + (size_t)N_NODES * 64;
    unsigned short* Wt2 = Wt1 + IN_DIM * HID_DIM;
    int* bcur = (int*)(Wt2 + HID_DIM * OUT_DIM);

    // 5 dispatches
    k_prep<<<49, 256, 0, stream>>>(W1, Wt1, W2, Wt2, bcur);
    k_mega1<<<GEMM1_GRID + NBLK_E, 256, 0, stream>>>(
        x, Wt1, support, erow, ecol, eval_, bcur, bucketed);
    k_spmm<true, true><<<NB, 1024, 0, stream>>>(
        bcur, bucketed, support, b1, agg1);
    k_gemm2<<<GEMM1_GRID, 256, 0, stream>>>(agg1, Wt2, support);
    k_spmm<false, false><<<NB, 1024, 0, stream>>>(
        bcur, bucketed, support, b2, out);
}

// Round 10
// 94.954 us; speedup vs baseline: 7.7772x; 7.7772x over previous
//
#include <hip/hip_runtime.h>

// GCN forward on MI355X (gfx950).
// R10: revert R9's LDS-atomic SpMM (shared-mem f32 atomicAdd = CAS loop,
// 349us — 7x regression). Back to R8's row-sorted gather structure; keep
// R9's one good idea: GEMM1 || bscatter fused in one dispatch (independent
// work, block-range split). 6 dispatches.

#define N_NODES 50000
#define N_EDGES 800000
#define IN_DIM  128
#define HID_DIM 64
#define OUT_DIM 64

#define NB   196         // row buckets (row >> 8)
#define EPB  4096        // edges per bscatter block
#define NBLK_E ((N_EDGES + EPB - 1) / EPB)   // 196
#define BCAP 5120        // padded region per bucket; E[cnt]=4096, sigma~64
#define GEMM1_GRID ((N_NODES + 31) / 32)     // 1563

typedef __attribute__((ext_vector_type(8))) short bf16x8;
typedef __attribute__((ext_vector_type(4))) float f32x4;

__device__ inline unsigned short f2bf(float x) {   // RNE fp32 -> bf16
    unsigned u = __float_as_uint(x);
    return (unsigned short)((u + 0x7FFFu + ((u >> 16) & 1u)) >> 16);
}
__device__ inline float bf2f(unsigned v) {
    return __uint_as_float(v << 16);
}

// ---------------- prep: weight transpose+bf16 convert, bcur zero ------
__global__ __launch_bounds__(256) void k_prep(
    const float* __restrict__ W1, unsigned short* __restrict__ Wt1,
    const float* __restrict__ W2, unsigned short* __restrict__ Wt2,
    int* __restrict__ bcur)
{
    int b = blockIdx.x, t = threadIdx.x;
    if (b < 32) {                       // IN_DIM*HID_DIM = 8192 = 32*256
        int e = b * 256 + t;
        int c = e / IN_DIM, k = e % IN_DIM;
        Wt1[c * IN_DIM + k] = f2bf(W1[k * HID_DIM + c]);
    } else if (b < 48) {                // HID_DIM*OUT_DIM = 4096 = 16*256
        int e2 = (b - 32) * 256 + t;
        int c = e2 / HID_DIM, k = e2 % HID_DIM;
        Wt2[c * HID_DIM + k] = f2bf(W2[k * OUT_DIM + c]);
    } else {
        if (t < NB) bcur[t] = 0;
    }
}

// ---------------- MFMA GEMM body (32 rows/block, 4 waves) -------------
// Both LDS tiles XOR-swizzled (byte ^= (row&7)<<4).
template <int K, bool IN_BF16>
__device__ __forceinline__ void gemm_body(
    unsigned short* __restrict__ Al, unsigned short* __restrict__ Bl,
    const void* __restrict__ Xv, const unsigned short* __restrict__ Wt,
    unsigned short* __restrict__ out, int bid, int t)
{
    int m0 = bid * 32;
    #pragma unroll
    for (int i = 0; i < K / 32; ++i) {
        int u4 = i * 256 + t;                 // uint4 index
        int col = (u4 * 8) / K, k = (u4 * 8) % K;
        uint4 w = ((const uint4*)Wt)[u4];
        int byte = (col * K + k) * 2;
        byte ^= ((col & 7) << 4);
        *(uint4*)((char*)Bl + byte) = w;
    }
    if (IN_BF16) {
        const unsigned short* X = (const unsigned short*)Xv;
        int row = t / (K / 8), k = (t % (K / 8)) * 8;
        int grow = m0 + row;
        uint4 v = make_uint4(0, 0, 0, 0);
        if (grow < N_NODES)
            v = *(const uint4*)(X + (size_t)grow * K + k);
        int byte = (row * K + k) * 2;
        byte ^= ((row & 7) << 4);
        *(uint4*)((char*)Al + byte) = v;
    } else {
        const float* X = (const float*)Xv;
        #pragma unroll
        for (int i = 0; i < K / 64; ++i) {
            int f8 = i * 256 + t;             // 8-float group
            int row = (f8 * 8) / K, k = (f8 * 8) % K;
            int grow = m0 + row;
            float4 xa = make_float4(0.f, 0.f, 0.f, 0.f), xb = xa;
            if (grow < N_NODES) {
                const float4* src = (const float4*)(X + (size_t)grow * K + k);
                xa = src[0];
                xb = src[1];
            }
            uint4 v;
            v.x = (unsigned)f2bf(xa.x) | ((unsigned)f2bf(xa.y) << 16);
            v.y = (unsigned)f2bf(xa.z) | ((unsigned)f2bf(xa.w) << 16);
            v.z = (unsigned)f2bf(xb.x) | ((unsigned)f2bf(xb.y) << 16);
            v.w = (unsigned)f2bf(xb.z) | ((unsigned)f2bf(xb.w) << 16);
            int byte = (row * K + k) * 2;
            byte ^= ((row & 7) << 4);
            *(uint4*)((char*)Al + byte) = v;
        }
    }
    __syncthreads();

    int w = t >> 6, l = t & 63;
    int lr0 = (w & 1) * 16;
    int c0  = (w >> 1) * 32;
    int lrow = lr0 + (l & 15);
    int kb = (l >> 4) * 8;
    int col0 = c0 + (l & 15), col1 = col0 + 16;
    f32x4 acc0 = {0.f, 0.f, 0.f, 0.f}, acc1 = {0.f, 0.f, 0.f, 0.f};
    #pragma unroll
    for (int kc = 0; kc < K / 32; ++kc) {
        int ka = kc * 32 + kb;
        int ab = (lrow * K + ka) * 2;  ab ^= ((lrow & 7) << 4);
        int bb0 = (col0 * K + ka) * 2; bb0 ^= ((col0 & 7) << 4);
        int bb1 = (col1 * K + ka) * 2; bb1 ^= ((col1 & 7) << 4);
        bf16x8 a  = *(const bf16x8*)((const char*)Al + ab);
        bf16x8 b0 = *(const bf16x8*)((const char*)Bl + bb0);
        bf16x8 b1 = *(const bf16x8*)((const char*)Bl + bb1);
        acc0 = __builtin_amdgcn_mfma_f32_16x16x32_bf16(a, b0, acc0, 0, 0, 0);
        acc1 = __builtin_amdgcn_mfma_f32_16x16x32_bf16(a, b1, acc1, 0, 0, 0);
    }
    int grow0 = m0 + lr0 + (l >> 4) * 4;
    #pragma unroll
    for (int j = 0; j < 4; ++j) {
        int gr = grow0 + j;
        if (gr < N_NODES) {
            out[(size_t)gr * 64 + col0] = f2bf(acc0[j]);
            out[(size_t)gr * 64 + col1] = f2bf(acc1[j]);
        }
    }
}

// ---------------- mega1: GEMM1 (blocks < GEMM1_GRID) || bscatter ------
// Independent: GEMM1 reads x/Wt1 -> support; bscatter reads edges ->
// bucketed. Shared-memory union: GEMM 24KB; bscatter 1.6KB.
__global__ __launch_bounds__(256) void k_mega1(
    const float* __restrict__ X, const unsigned short* __restrict__ Wt1,
    unsigned short* __restrict__ support,
    const int* __restrict__ erow, const int* __restrict__ ecol,
    const float* __restrict__ eval_, int* __restrict__ bcur,
    uint2* __restrict__ bucketed)
{
    __shared__ __align__(16) unsigned char smem[24576];
    int t = threadIdx.x;
    if (blockIdx.x < GEMM1_GRID) {
        gemm_body<IN_DIM, false>((unsigned short*)smem,
                                 (unsigned short*)(smem + 8192),
                                 X, Wt1, support, blockIdx.x, t);
        return;
    }
    // ---- bscatter: edges into padded bucket regions ----
    // word0 = col (16b) | rowlow (8b) << 16; word1 = val bits.
    int* lc    = (int*)smem;
    int* lbase = lc + NB;
    int blk = blockIdx.x - GEMM1_GRID;
    for (int i = t; i < NB; i += 256) lc[i] = 0;
    __syncthreads();
    int base = blk * EPB;
    int bkt[16], rnk[16];
    #pragma unroll 4
    for (int i = 0; i < 16; ++i) {
        int e = base + i * 256 + t;
        bkt[i] = -1;
        if (e < N_EDGES) {
            bkt[i] = erow[e] >> 8;
            rnk[i] = atomicAdd(&lc[bkt[i]], 1);
        }
    }
    __syncthreads();
    for (int i = t; i < NB; i += 256)
        lbase[i] = lc[i] ? atomicAdd(&bcur[i], lc[i]) : 0;
    __syncthreads();
    #pragma unroll 4
    for (int i = 0; i < 16; ++i) {
        int e = base + i * 256 + t;
        if (bkt[i] >= 0) {
            unsigned r = (unsigned)erow[e];
            unsigned w0 = (unsigned)ecol[e] | ((r & 255u) << 16);
            bucketed[(size_t)bkt[i] * BCAP + lbase[bkt[i]] + rnk[i]] =
                make_uint2(w0, __float_as_uint(eval_[e]));
        }
    }
}

// ---------------- pass B: one block per bucket ------------------------
// LDS-cache the bucket's edges; per-row count -> in-block scan ->
// offs2[row]=(start,end) -> row-sorted scatter into pairs.
__global__ __launch_bounds__(256) void k_bfinal(
    const int* __restrict__ bcur, const uint2* __restrict__ bucketed,
    uint2* __restrict__ pairs, int2* __restrict__ offs2)
{
    __shared__ uint2 ebuf[BCAP];        // 40 KB
    __shared__ int rcnt[256];
    __shared__ int rsc[256];
    int t = threadIdx.x, b = blockIdx.x;
    int ne = bcur[b];
    int base0 = b * BCAP;
    rcnt[t] = 0;
    __syncthreads();
    for (int i = t; i < ne; i += 256) {
        uint2 p = bucketed[(size_t)base0 + i];
        ebuf[i] = p;
        atomicAdd(&rcnt[(p.x >> 16) & 255], 1);
    }
    __syncthreads();
    int v = rcnt[t];
    rsc[t] = v;
    __syncthreads();
    #pragma unroll
    for (int off = 1; off < 256; off <<= 1) {
        int add = (t >= off) ? rsc[t - off] : 0;
        __syncthreads();
        rsc[t] += add;
        __syncthreads();
    }
    int start = base0 + rsc[t] - v;
    int gr = (b << 8) + t;
    if (gr < N_NODES) offs2[gr] = make_int2(start, start + v);
    rcnt[t] = start;                    // becomes row cursor
    __syncthreads();
    for (int i = t; i < ne; i += 256) {
        uint2 p = ebuf[i];
        int pos = atomicAdd(&rcnt[(p.x >> 16) & 255], 1);
        pairs[pos] = make_uint2(p.x & 0xFFFFu, p.y);
    }
}

// ---------------- gather SpMM: bf16 dense, 8-way edge unroll ----------
template <bool APPLY_RELU, bool OUT_BF16>
__global__ __launch_bounds__(256) void k_gather(
    const int2* __restrict__ offs2, const uint2* __restrict__ pairs,
    const unsigned short* __restrict__ dense, const float* __restrict__ bias,
    void* __restrict__ outp)
{
    int t = threadIdx.x;
    int r = __builtin_amdgcn_readfirstlane(blockIdx.x * 4 + (t >> 6));
    int d = t & 63;
    int2 oe = offs2[r];
    int e0 = oe.x, e1 = oe.y;
    float a[8];
    a[0] = bias[d];
    #pragma unroll
    for (int i = 1; i < 8; ++i) a[i] = 0.f;
    int e = e0;
    for (; e + 8 <= e1; e += 8) {
        uint2 p[8];
        #pragma unroll
        for (int i = 0; i < 8; ++i) p[i] = pairs[e + i];
        unsigned v[8];
        #pragma unroll
        for (int i = 0; i < 8; ++i) v[i] = dense[(size_t)p[i].x * 64u + d];
        #pragma unroll
        for (int i = 0; i < 8; ++i)
            a[i] = fmaf(__uint_as_float(p[i].y), bf2f(v[i]), a[i]);
    }
    if (e + 4 <= e1) {
        uint2 p[4];
        #pragma unroll
        for (int i = 0; i < 4; ++i) p[i] = pairs[e + i];
        unsigned v[4];
        #pragma unroll
        for (int i = 0; i < 4; ++i) v[i] = dense[(size_t)p[i].x * 64u + d];
        #pragma unroll
        for (int i = 0; i < 4; ++i)
            a[i] = fmaf(__uint_as_float(p[i].y), bf2f(v[i]), a[i]);
        e += 4;
    }
    for (; e < e1; ++e) {
        uint2 p = pairs[e];
        a[0] = fmaf(__uint_as_float(p.y),
                    bf2f(dense[(size_t)p.x * 64u + d]), a[0]);
    }
    float acc = ((a[0] + a[1]) + (a[2] + a[3])) +
                ((a[4] + a[5]) + (a[6] + a[7]));
    if (APPLY_RELU) acc = fmaxf(acc, 0.f);
    if (OUT_BF16)
        ((unsigned short*)outp)[(size_t)r * 64 + d] = f2bf(acc);
    else
        ((float*)outp)[(size_t)r * 64 + d] = acc;
}

// ---------------- GEMM2 standalone (K=64, bf16 in) --------------------
__global__ __launch_bounds__(256) void k_gemm2(
    const unsigned short* __restrict__ X, const unsigned short* __restrict__ Wt,
    unsigned short* __restrict__ out)
{
    __shared__ unsigned short Al[32 * HID_DIM];
    __shared__ unsigned short Bl[64 * HID_DIM];
    gemm_body<HID_DIM, true>(Al, Bl, X, Wt, out, blockIdx.x, threadIdx.x);
}

extern "C" void kernel_launch(void* const* d_in, const int* in_sizes, int n_in,
                              void* d_out, int out_size, void* d_ws, size_t ws_size,
                              hipStream_t stream)
{
    const float* x     = (const float*)d_in[0];
    const int*   erow  = (const int*)d_in[1];
    const int*   ecol  = (const int*)d_in[2];
    const float* eval_ = (const float*)d_in[3];
    const float* W1    = (const float*)d_in[4];
    const float* b1    = (const float*)d_in[5];
    const float* W2    = (const float*)d_in[6];
    const float* b2    = (const float*)d_in[7];
    float* out = (float*)d_out;

    // ws (~30 MB): padded pairs 8.03MB | padded bucketed 8.03MB |
    // support bf16 6.4MB | agg1 bf16 6.4MB | Wt1 | Wt2 | bcur | offs2
    uint2* pairs    = (uint2*)d_ws;
    uint2* bucketed = pairs + (size_t)NB * BCAP;
    unsigned short* support = (unsigned short*)(bucketed + (size_t)NB * BCAP);
    unsigned short* agg1 = support + (size_t)N_NODES * 64;
    unsigned short* Wt1 = agg1 + (size_t)N_NODES * 64;
    unsigned short* Wt2 = Wt1 + IN_DIM * HID_DIM;
    int*  bcur  = (int*)(Wt2 + HID_DIM * OUT_DIM);
    int2* offs2 = (int2*)(bcur + NB + 2);      // 8B-aligned

    const int row_grid = N_NODES / 4;          // 12500 (gather)

    // 6 dispatches
    k_prep<<<49, 256, 0, stream>>>(W1, Wt1, W2, Wt2, bcur);
    k_mega1<<<GEMM1_GRID + NBLK_E, 256, 0, stream>>>(
        x, Wt1, support, erow, ecol, eval_, bcur, bucketed);
    k_bfinal<<<NB, 256, 0, stream>>>(bcur, bucketed, pairs, offs2);
    k_gather<true, true><<<row_grid, 256, 0, stream>>>(
        offs2, pairs, support, b1, agg1);
    k_gemm2<<<GEMM1_GRID, 256, 0, stream>>>(agg1, Wt2, support);
    k_gather<false, false><<<row_grid, 256, 0, stream>>>(
        offs2, pairs, support, b2, out);
}